// Round 1
// baseline (195.828 us; speedup 1.0000x reference)
//
#include <hip/hip_runtime.h>

// Problem constants (from reference setup_inputs)
#define BB   64
#define SS   512
#define AA   8
#define DD   128
#define CC   1024
#define NCAND (BB * CC)   // 65536

// Output layout (flat fp32, tuple concatenated in return order)
#define OFF_REPR  0ULL
#define SZ_REPR   ((size_t)BB * CC * DD)        // 8388608
#define OFF_LABEL (OFF_REPR + SZ_REPR)          // 8388608
#define OFF_NUM   (OFF_LABEL + (size_t)BB * CC) // 8454144
#define OFF_LEN   (OFF_NUM + 1ULL)              // 8454145
#define OFF_MASK  (OFF_LEN + (size_t)BB)        // 8454209
#define OFF_LOC   (OFF_MASK + (size_t)BB * CC)  // 8519745

// Kernel A: gather + mask the representation rows.
// 32 lanes per candidate, one float4 (16B) per lane -> 512B coalesced segment.
// 256 threads/block = 8 candidates/block; grid = 65536/8 = 8192 blocks.
__global__ __launch_bounds__(256) void repr_kernel(
    const float* __restrict__ word_repr,
    const int*   __restrict__ anchor_loc,
    const int*   __restrict__ cand_idx,
    float*       __restrict__ out)
{
    const int tid  = threadIdx.x;
    const int lane = tid & 31;
    const int i    = blockIdx.x * 8 + (tid >> 5);   // candidate id, < 65536

    // Index reads: same address across the 32-lane group -> broadcast loads.
    const int b = cand_idx[3 * i + 0];
    const int w = cand_idx[3 * i + 1];
    const int a = cand_idx[3 * i + 2];
    const int base = (b * SS + w) * AA + a;          // row index into (B,S,A)

    const int l0 = anchor_loc[2 * base + 0];
    const int l1 = anchor_loc[2 * base + 1];
    const float m = (l0 != l1) ? 1.0f : 0.0f;

    const float4 v = ((const float4*)word_repr)[(size_t)base * 32 + lane];
    float4 r;
    r.x = v.x * m; r.y = v.y * m; r.z = v.z * m; r.w = v.w * m;
    ((float4*)(out + OFF_REPR))[(size_t)i * 32 + lane] = r;
}

// Kernel B: per-candidate scalars (label, mask, loc) + per-batch mask-sum
// reduction -> candidate_len.  One block (256 threads) per batch, 4
// candidates per thread.
__global__ __launch_bounds__(256) void scalar_kernel(
    const int* __restrict__ anchor_cls,
    const int* __restrict__ anchor_loc,
    const int* __restrict__ cand_idx,
    const int* __restrict__ cnum,
    float*     __restrict__ out)
{
    const int b   = blockIdx.x;
    const int tid = threadIdx.x;

    float msum = 0.0f;
#pragma unroll
    for (int j = 0; j < CC / 256; ++j) {
        const int c = tid + j * 256;
        const int i = b * CC + c;
        const int bb = cand_idx[3 * i + 0];
        const int w  = cand_idx[3 * i + 1];
        const int a  = cand_idx[3 * i + 2];
        const int base = (bb * SS + w) * AA + a;
        const int l0 = anchor_loc[2 * base + 0];
        const int l1 = anchor_loc[2 * base + 1];
        const float m = (l0 != l1) ? 1.0f : 0.0f;
        msum += m;
        out[OFF_LABEL + i] = (float)anchor_cls[base];
        out[OFF_MASK  + i] = m;
        out[OFF_LOC + 2 * (size_t)i + 0] = (float)l0;
        out[OFF_LOC + 2 * (size_t)i + 1] = (float)l1;
    }

    // wave(64) shuffle reduce, then LDS across the 4 waves
#pragma unroll
    for (int off = 32; off > 0; off >>= 1)
        msum += __shfl_down(msum, off, 64);

    __shared__ float sm[4];
    if ((tid & 63) == 0) sm[tid >> 6] = msum;
    __syncthreads();
    if (tid == 0) {
        const float s = sm[0] + sm[1] + sm[2] + sm[3];
        out[OFF_LEN + b] = fmaxf(s, 1.0f);
        if (b == 0) out[OFF_NUM] = (float)(*cnum);  // batch_candidate_num
    }
}

extern "C" void kernel_launch(void* const* d_in, const int* in_sizes, int n_in,
                              void* d_out, int out_size, void* d_ws, size_t ws_size,
                              hipStream_t stream) {
    const float* word_repr  = (const float*)d_in[0];
    const int*   anchor_cls = (const int*)  d_in[1];
    const int*   anchor_loc = (const int*)  d_in[2];
    const int*   cand_idx   = (const int*)  d_in[3];
    const int*   cnum       = (const int*)  d_in[4];
    float*       out        = (float*)      d_out;

    repr_kernel<<<dim3(NCAND / 8), dim3(256), 0, stream>>>(
        word_repr, anchor_loc, cand_idx, out);
    scalar_kernel<<<dim3(BB), dim3(256), 0, stream>>>(
        anchor_cls, anchor_loc, cand_idx, cnum, out);
}

// Round 2
// 193.263 us; speedup vs baseline: 1.0133x; 1.0133x over previous
//
#include <hip/hip_runtime.h>

// Problem constants (from reference setup_inputs)
#define BB   64
#define SS   512
#define AA   8
#define DD   128
#define CC   1024
#define NCAND (BB * CC)   // 65536

// Output layout (flat fp32, tuple concatenated in return order)
#define OFF_REPR  0ULL
#define SZ_REPR   ((size_t)BB * CC * DD)        // 8388608
#define OFF_LABEL (OFF_REPR + SZ_REPR)          // 8388608
#define OFF_NUM   (OFF_LABEL + (size_t)BB * CC) // 8454144
#define OFF_LEN   (OFF_NUM + 1ULL)              // 8454145
#define OFF_MASK  (OFF_LEN + (size_t)BB)        // 8454209
#define OFF_LOC   (OFF_MASK + (size_t)BB * CC)  // 8519745

// Fused kernel: 8192 blocks x 256 threads.
//  - Every block: 8 candidates, 32 lanes each -> float4 gather+mask+store
//    (512B coalesced segments). Lane 0 of each 32-group writes label/mask/loc.
//  - Blocks [0,64): additionally compute candidate_len for batch==blockIdx
//    (redundant re-read of idx/loc for 1024 candidates: ~20KB/block, noise).
//  - Block 0 thread 0 writes batch_candidate_num.
__global__ __launch_bounds__(256) void fused_kernel(
    const float* __restrict__ word_repr,
    const int*   __restrict__ anchor_cls,
    const int*   __restrict__ anchor_loc,
    const int*   __restrict__ cand_idx,
    const int*   __restrict__ cnum,
    float*       __restrict__ out)
{
    const int tid  = threadIdx.x;
    const int lane = tid & 31;
    const int i    = blockIdx.x * 8 + (tid >> 5);   // candidate id, < 65536

    // Broadcast loads (uniform across the 32-lane group).
    const int b = cand_idx[3 * i + 0];
    const int w = cand_idx[3 * i + 1];
    const int a = cand_idx[3 * i + 2];
    const int base = (b * SS + w) * AA + a;          // row index into (B,S,A)

    const int2 loc = ((const int2*)anchor_loc)[base];
    const float m = (loc.x != loc.y) ? 1.0f : 0.0f;

    const float4 v = ((const float4*)word_repr)[(size_t)base * 32 + lane];
    float4 r;
    r.x = v.x * m; r.y = v.y * m; r.z = v.z * m; r.w = v.w * m;
    ((float4*)(out + OFF_REPR))[(size_t)i * 32 + lane] = r;

    if (lane == 0) {
        out[OFF_LABEL + i] = (float)anchor_cls[base];
        out[OFF_MASK  + i] = m;
        out[OFF_LOC + 2 * (size_t)i + 0] = (float)loc.x;
        out[OFF_LOC + 2 * (size_t)i + 1] = (float)loc.y;
    }

    // candidate_len: first 64 blocks each reduce one batch's 1024 masks.
    if (blockIdx.x < BB) {
        const int bb = blockIdx.x;
        float msum = 0.0f;
#pragma unroll
        for (int j = 0; j < CC / 256; ++j) {
            const int c  = tid + j * 256;
            const int i2 = bb * CC + c;
            const int b2 = cand_idx[3 * i2 + 0];
            const int w2 = cand_idx[3 * i2 + 1];
            const int a2 = cand_idx[3 * i2 + 2];
            const int2 l2 = ((const int2*)anchor_loc)[(b2 * SS + w2) * AA + a2];
            msum += (l2.x != l2.y) ? 1.0f : 0.0f;
        }
#pragma unroll
        for (int off = 32; off > 0; off >>= 1)
            msum += __shfl_down(msum, off, 64);

        __shared__ float sm[4];
        if ((tid & 63) == 0) sm[tid >> 6] = msum;
        __syncthreads();
        if (tid == 0) {
            const float s = sm[0] + sm[1] + sm[2] + sm[3];
            out[OFF_LEN + bb] = fmaxf(s, 1.0f);
            if (bb == 0) out[OFF_NUM] = (float)(*cnum);
        }
    }
}

extern "C" void kernel_launch(void* const* d_in, const int* in_sizes, int n_in,
                              void* d_out, int out_size, void* d_ws, size_t ws_size,
                              hipStream_t stream) {
    const float* word_repr  = (const float*)d_in[0];
    const int*   anchor_cls = (const int*)  d_in[1];
    const int*   anchor_loc = (const int*)  d_in[2];
    const int*   cand_idx   = (const int*)  d_in[3];
    const int*   cnum       = (const int*)  d_in[4];
    float*       out        = (float*)      d_out;

    fused_kernel<<<dim3(NCAND / 8), dim3(256), 0, stream>>>(
        word_repr, anchor_cls, anchor_loc, cand_idx, cnum, out);
}